// Round 2
// baseline (253.982 us; speedup 1.0000x reference)
//
#include <hip/hip_runtime.h>

#define BATCH 32
#define KVLEN 2048
#define HDIM 1024
#define NHEAD 16
#define DHEAD 64
#define FFDIM 4096
#define LN_EPS 1e-5f
#define NCHUNK 8
#define CHUNK_ROWS 256   // KVLEN / NCHUNK

// ---------------------------------------------------------------------------
// GEMV over K=1024: out[b][j] = act(dot(in[b,:], W[j,:]) [+bias] [+res])
// One wave owns 4 consecutive j rows; weight fragments persist in registers
// across the 32-batch loop (weights hit HBM exactly once). Merged-tree
// reduction: 7 shuffles per batch for all 4 rows.
// blockIdx.y = split-K chunk (offsets via *_coff).
// ---------------------------------------------------------------------------
template<bool RELU, bool HAS_BIAS, bool HAS_RES>
__global__ __launch_bounds__(256) void gemv_k1024(
    const float* __restrict__ in, int in_bstride, int in_coff,
    const float* __restrict__ W, int w_jstride, int w_coff,
    const float* __restrict__ bias,
    const float* __restrict__ res, int res_bstride,
    float* __restrict__ out, int out_bstride, int out_coff,
    int nJ)
{
    const int wave = (int)((blockIdx.x * blockDim.x + threadIdx.x) >> 6);
    const int lane = (int)(threadIdx.x & 63);
    const int j0 = wave * 4;
    if (j0 >= nJ) return;
    const int c = (int)blockIdx.y;
    const float* inp = in + (size_t)c * in_coff;
    const float* Wp  = W  + (size_t)c * w_coff;
    float* outp      = out + (size_t)c * out_coff;

    float4 w[4][4];
#pragma unroll
    for (int jj = 0; jj < 4; ++jj) {
        const float4* wr = (const float4*)(Wp + (size_t)(j0 + jj) * w_jstride);
#pragma unroll
        for (int i = 0; i < 4; ++i) w[jj][i] = wr[lane + i * 64];
    }

    for (int b = 0; b < BATCH; ++b) {
        const float4* xr = (const float4*)(inp + (size_t)b * in_bstride);
        float4 xv[4];
#pragma unroll
        for (int i = 0; i < 4; ++i) xv[i] = xr[lane + i * 64];
        float s[4];
#pragma unroll
        for (int jj = 0; jj < 4; ++jj) {
            float a = 0.f;
#pragma unroll
            for (int i = 0; i < 4; ++i)
                a += w[jj][i].x * xv[i].x + w[jj][i].y * xv[i].y
                   + w[jj][i].z * xv[i].z + w[jj][i].w * xv[i].w;
            s[jj] = a;
        }
        // merged tree: fold 4 values into 1 reg (3 shfl), then 4 butterfly levels
        const bool b0 = (lane & 1), b1 = (lane & 2);
        float a0 = b0 ? s[0] : s[1];
        float t0 = (b0 ? s[1] : s[0]) + __shfl_xor(a0, 1, 64);
        float a1 = b0 ? s[2] : s[3];
        float t1 = (b0 ? s[3] : s[2]) + __shfl_xor(a1, 1, 64);
        float a2 = b1 ? t0 : t1;
        float v  = (b1 ? t1 : t0) + __shfl_xor(a2, 2, 64);
        v += __shfl_xor(v, 4, 64);
        v += __shfl_xor(v, 8, 64);
        v += __shfl_xor(v, 16, 64);
        v += __shfl_xor(v, 32, 64);
        // lane holds full sum of row j0 + (lane&3); lanes 0..3 write
        if (lane < 4) {
            const int j = j0 + lane;
            float o = v;
            if (HAS_BIAS) o += bias[j];
            if (HAS_RES)  o += res[(size_t)b * res_bstride + j];
            if (RELU)     o = fmaxf(o, 0.f);
            outp[(size_t)b * out_bstride + j] = o;
        }
    }
}

// ---------------------------------------------------------------------------
// Copy ik/iv slices of qkv to d_out (outputs 1 and 2).
// ---------------------------------------------------------------------------
__global__ __launch_bounds__(256) void copy_ikiv(const float* __restrict__ qkv,
                                                 float* __restrict__ out)
{
    int idx = (int)(blockIdx.x * blockDim.x + threadIdx.x);   // 0..32767
    int b = idx >> 10, j = idx & 1023;
    out[32768 + idx] = qkv[(size_t)b * 3072 + 1024 + j];
    out[65536 + idx] = qkv[(size_t)b * 3072 + 2048 + j];
}

// ---------------------------------------------------------------------------
// Attention pass 1: one block per (b, chunk). 1024 threads = 16 waves.
// Each wave streams FULL contiguous KV rows (64 lanes x 16 floats = 4 KB),
// scoring all 16 heads simultaneously: lane l owns head h=l>>2,
// dims (l&3)*16 .. +16. Per-head reduce = 2 shfl_xor in 4-lane groups.
// Online softmax per head in registers; 16 waves combined via LDS.
// Emits per-chunk partial {m, l, acc[1024]} for the finish kernel.
// Appended token (row 2048, from qkv) handled by chunk 7 / wave 0.
// ---------------------------------------------------------------------------
__global__ __launch_bounds__(1024) void attn_part(
    const float* __restrict__ qkv,       // [32][3072]
    const float* __restrict__ k_cache,   // [32][2048][1024]
    const float* __restrict__ v_cache,
    float* __restrict__ pacc,            // [32][8][1024]  (p-layout)
    float* __restrict__ pm,              // [32][8][16]
    float* __restrict__ pl)              // [32][8][16]
{
    const int b = (int)(blockIdx.x >> 3);
    const int c = (int)(blockIdx.x & 7);
    const int tid = (int)threadIdx.x;
    const int w = tid >> 6;      // wave 0..15
    const int l = tid & 63;

    // persistent q fragment: lane l covers dims [l*16, l*16+16)
    const float* qrow = qkv + (size_t)b * 3072;
    float4 q[4];
#pragma unroll
    for (int i = 0; i < 4; ++i) q[i] = ((const float4*)(qrow + l * 16))[i];

    float m = -1e30f, ls = 0.f;
    float4 acc[4];
#pragma unroll
    for (int i = 0; i < 4; ++i) acc[i] = make_float4(0.f, 0.f, 0.f, 0.f);

    const float* kb = k_cache + ((size_t)b * KVLEN + (size_t)c * CHUNK_ROWS) * HDIM + l * 16;
    const float* vb = v_cache + ((size_t)b * KVLEN + (size_t)c * CHUNK_ROWS) * HDIM + l * 16;

#pragma unroll
    for (int i = 0; i < 16; ++i) {
        const int r = w + i * 16;   // row within chunk
        const float4* kr = (const float4*)(kb + (size_t)r * HDIM);
        const float4* vr = (const float4*)(vb + (size_t)r * HDIM);
        float4 k0 = kr[0], k1 = kr[1], k2 = kr[2], k3 = kr[3];
        float4 v0 = vr[0], v1 = vr[1], v2 = vr[2], v3 = vr[3];
        float s = k0.x*q[0].x + k0.y*q[0].y + k0.z*q[0].z + k0.w*q[0].w
                + k1.x*q[1].x + k1.y*q[1].y + k1.z*q[1].z + k1.w*q[1].w
                + k2.x*q[2].x + k2.y*q[2].y + k2.z*q[2].z + k2.w*q[2].w
                + k3.x*q[3].x + k3.y*q[3].y + k3.z*q[3].z + k3.w*q[3].w;
        s += __shfl_xor(s, 1, 64);
        s += __shfl_xor(s, 2, 64);
        s *= 0.125f;
        const float mn = fmaxf(m, s);
        const float corr = __expf(m - mn);
        const float p = __expf(s - mn);
        ls = ls * corr + p;
        acc[0].x = acc[0].x*corr + p*v0.x; acc[0].y = acc[0].y*corr + p*v0.y;
        acc[0].z = acc[0].z*corr + p*v0.z; acc[0].w = acc[0].w*corr + p*v0.w;
        acc[1].x = acc[1].x*corr + p*v1.x; acc[1].y = acc[1].y*corr + p*v1.y;
        acc[1].z = acc[1].z*corr + p*v1.z; acc[1].w = acc[1].w*corr + p*v1.w;
        acc[2].x = acc[2].x*corr + p*v2.x; acc[2].y = acc[2].y*corr + p*v2.y;
        acc[2].z = acc[2].z*corr + p*v2.z; acc[2].w = acc[2].w*corr + p*v2.w;
        acc[3].x = acc[3].x*corr + p*v3.x; acc[3].y = acc[3].y*corr + p*v3.y;
        acc[3].z = acc[3].z*corr + p*v3.z; acc[3].w = acc[3].w*corr + p*v3.w;
        m = mn;
    }

    // appended token (global row 2048) from qkv: same lane->dim layout
    if (c == NCHUNK - 1 && w == 0) {
        const float4* kr = (const float4*)(qkv + (size_t)b * 3072 + 1024 + l * 16);
        const float4* vr = (const float4*)(qkv + (size_t)b * 3072 + 2048 + l * 16);
        float4 k0 = kr[0], k1 = kr[1], k2 = kr[2], k3 = kr[3];
        float4 v0 = vr[0], v1 = vr[1], v2 = vr[2], v3 = vr[3];
        float s = k0.x*q[0].x + k0.y*q[0].y + k0.z*q[0].z + k0.w*q[0].w
                + k1.x*q[1].x + k1.y*q[1].y + k1.z*q[1].z + k1.w*q[1].w
                + k2.x*q[2].x + k2.y*q[2].y + k2.z*q[2].z + k2.w*q[2].w
                + k3.x*q[3].x + k3.y*q[3].y + k3.z*q[3].z + k3.w*q[3].w;
        s += __shfl_xor(s, 1, 64);
        s += __shfl_xor(s, 2, 64);
        s *= 0.125f;
        const float mn = fmaxf(m, s);
        const float corr = __expf(m - mn);
        const float p = __expf(s - mn);
        ls = ls * corr + p;
        acc[0].x = acc[0].x*corr + p*v0.x; acc[0].y = acc[0].y*corr + p*v0.y;
        acc[0].z = acc[0].z*corr + p*v0.z; acc[0].w = acc[0].w*corr + p*v0.w;
        acc[1].x = acc[1].x*corr + p*v1.x; acc[1].y = acc[1].y*corr + p*v1.y;
        acc[1].z = acc[1].z*corr + p*v1.z; acc[1].w = acc[1].w*corr + p*v1.w;
        acc[2].x = acc[2].x*corr + p*v2.x; acc[2].y = acc[2].y*corr + p*v2.y;
        acc[2].z = acc[2].z*corr + p*v2.z; acc[2].w = acc[2].w*corr + p*v2.w;
        acc[3].x = acc[3].x*corr + p*v3.x; acc[3].y = acc[3].y*corr + p*v3.y;
        acc[3].z = acc[3].z*corr + p*v3.z; acc[3].w = acc[3].w*corr + p*v3.w;
        m = mn;
    }

    // cross-wave combine via LDS (once per block -- conflicts negligible)
    __shared__ float sacc[16][1024];
    __shared__ float sm[16][16];
    __shared__ float sl[16][16];
    float* dst = &sacc[w][l * 16];
#pragma unroll
    for (int i = 0; i < 4; ++i) ((float4*)dst)[i] = acc[i];
    if ((l & 3) == 0) { sm[w][l >> 2] = m; sl[w][l >> 2] = ls; }
    __syncthreads();

    // thread p combines position p over 16 waves; h = p>>6 (== wave id of tid)
    const int p = tid;
    const int h = p >> 6;
    float M = -1e30f;
#pragma unroll
    for (int w2 = 0; w2 < 16; ++w2) M = fmaxf(M, sm[w2][h]);
    float L = 0.f, o = 0.f;
#pragma unroll
    for (int w2 = 0; w2 < 16; ++w2) {
        const float f = __expf(sm[w2][h] - M);
        L += sl[w2][h] * f;
        o += sacc[w2][p] * f;
    }
    pacc[((size_t)b * NCHUNK + c) * 1024 + p] = o;
    if ((p & 63) == 0) {
        pm[((size_t)b * NCHUNK + c) * 16 + h] = M;
        pl[((size_t)b * NCHUNK + c) * 16 + h] = L;
    }
}

// ---------------------------------------------------------------------------
// Attention pass 2: merge 8 chunk partials per (b, position), write attn_out.
// p-layout: p -> (h = p>>6, d = ((p>>4)&3)*16 + (p&15)).
// ---------------------------------------------------------------------------
__global__ __launch_bounds__(1024) void attn_finish(
    const float* __restrict__ pacc, const float* __restrict__ pm,
    const float* __restrict__ pl, float* __restrict__ attn_out)
{
    const int b = (int)blockIdx.x;
    const int p = (int)threadIdx.x;
    const int h = p >> 6;
    float M = -1e30f;
#pragma unroll
    for (int c = 0; c < NCHUNK; ++c)
        M = fmaxf(M, pm[((size_t)b * NCHUNK + c) * 16 + h]);
    float L = 0.f, o = 0.f;
#pragma unroll
    for (int c = 0; c < NCHUNK; ++c) {
        const float f = __expf(pm[((size_t)b * NCHUNK + c) * 16 + h] - M);
        L += pl[((size_t)b * NCHUNK + c) * 16 + h] * f;
        o += pacc[((size_t)b * NCHUNK + c) * 1024 + p] * f;
    }
    const int d = ((p >> 4) & 3) * 16 + (p & 15);
    attn_out[(size_t)b * HDIM + h * DHEAD + d] = o / L;
}

// ---------------------------------------------------------------------------
// Row LayerNorm: 1 block per batch row of 1024.
// ---------------------------------------------------------------------------
__global__ __launch_bounds__(256) void ln_kernel(const float* __restrict__ in,
    const float* __restrict__ w, const float* __restrict__ bv,
    float* __restrict__ out)
{
    const int b = (int)blockIdx.x, tid = (int)threadIdx.x;
    const float4 v = ((const float4*)(in + (size_t)b * HDIM))[tid];
    float sum = v.x + v.y + v.z + v.w;
    float sq  = v.x * v.x + v.y * v.y + v.z * v.z + v.w * v.w;
#pragma unroll
    for (int off = 1; off < 64; off <<= 1) {
        sum += __shfl_xor(sum, off, 64);
        sq  += __shfl_xor(sq,  off, 64);
    }
    __shared__ float s1[4], s2[4];
    const int wid = tid >> 6, lane = tid & 63;
    if (lane == 0) { s1[wid] = sum; s2[wid] = sq; }
    __syncthreads();
    sum = s1[0] + s1[1] + s1[2] + s1[3];
    sq  = s2[0] + s2[1] + s2[2] + s2[3];
    const float mu = sum * (1.f / HDIM);
    const float var = sq * (1.f / HDIM) - mu * mu;
    const float rstd = rsqrtf(var + LN_EPS);
    const float4 wv = ((const float4*)w)[tid];
    const float4 bb = ((const float4*)bv)[tid];
    float4 o;
    o.x = (v.x - mu) * rstd * wv.x + bb.x;
    o.y = (v.y - mu) * rstd * wv.y + bb.y;
    o.z = (v.z - mu) * rstd * wv.z + bb.z;
    o.w = (v.w - mu) * rstd * wv.w + bb.w;
    ((float4*)(out + (size_t)b * HDIM))[tid] = o;
}

// ---------------------------------------------------------------------------
// MLP2 finish: sum 4 split-K partials + bias + residual, then LayerNorm -> d_out
// ---------------------------------------------------------------------------
__global__ __launch_bounds__(256) void mlp2_finish(const float* __restrict__ part,
    const float* __restrict__ x1, const float* __restrict__ mbias,
    const float* __restrict__ w, const float* __restrict__ bv,
    float* __restrict__ out)
{
    const int b = (int)blockIdx.x, tid = (int)threadIdx.x;
    float4 v = make_float4(0.f, 0.f, 0.f, 0.f);
#pragma unroll
    for (int c = 0; c < 4; ++c) {
        const float4 p = ((const float4*)(part + (size_t)c * 32768 + (size_t)b * HDIM))[tid];
        v.x += p.x; v.y += p.y; v.z += p.z; v.w += p.w;
    }
    const float4 r  = ((const float4*)(x1 + (size_t)b * HDIM))[tid];
    const float4 mb = ((const float4*)mbias)[tid];
    v.x += r.x + mb.x; v.y += r.y + mb.y; v.z += r.z + mb.z; v.w += r.w + mb.w;

    float sum = v.x + v.y + v.z + v.w;
    float sq  = v.x * v.x + v.y * v.y + v.z * v.z + v.w * v.w;
#pragma unroll
    for (int off = 1; off < 64; off <<= 1) {
        sum += __shfl_xor(sum, off, 64);
        sq  += __shfl_xor(sq,  off, 64);
    }
    __shared__ float s1[4], s2[4];
    const int wid = tid >> 6, lane = tid & 63;
    if (lane == 0) { s1[wid] = sum; s2[wid] = sq; }
    __syncthreads();
    sum = s1[0] + s1[1] + s1[2] + s1[3];
    sq  = s2[0] + s2[1] + s2[2] + s2[3];
    const float mu = sum * (1.f / HDIM);
    const float var = sq * (1.f / HDIM) - mu * mu;
    const float rstd = rsqrtf(var + LN_EPS);
    const float4 wv = ((const float4*)w)[tid];
    const float4 bb = ((const float4*)bv)[tid];
    float4 o;
    o.x = (v.x - mu) * rstd * wv.x + bb.x;
    o.y = (v.y - mu) * rstd * wv.y + bb.y;
    o.z = (v.z - mu) * rstd * wv.z + bb.z;
    o.w = (v.w - mu) * rstd * wv.w + bb.w;
    ((float4*)(out + (size_t)b * HDIM))[tid] = o;
}

extern "C" void kernel_launch(void* const* d_in, const int* in_sizes, int n_in,
                              void* d_out, int out_size, void* d_ws, size_t ws_size,
                              hipStream_t stream) {
    const float* x     = (const float*)d_in[0];
    const float* kc    = (const float*)d_in[1];
    const float* vc    = (const float*)d_in[2];
    const float* qkvw  = (const float*)d_in[3];
    const float* qkvb  = (const float*)d_in[4];
    const float* outw  = (const float*)d_in[5];
    const float* outb  = (const float*)d_in[6];
    const float* nw1   = (const float*)d_in[7];
    const float* nb1   = (const float*)d_in[8];
    const float* nw2   = (const float*)d_in[9];
    const float* nb2   = (const float*)d_in[10];
    const float* mw1   = (const float*)d_in[11];
    const float* mb1   = (const float*)d_in[12];
    const float* mw2   = (const float*)d_in[13];
    const float* mb2   = (const float*)d_in[14];
    float* out = (float*)d_out;

    float* ws   = (float*)d_ws;
    float* qkv  = ws;              // [32][3072]          = 98304
    float* pacc = ws + 98304;      // [32][8][1024]       = 262144
    float* pmb  = ws + 360448;     // [32][8][16]         = 4096
    float* plb  = ws + 364544;     // [32][8][16]         = 4096
    float* attn = ws + 368640;     // [32][1024]
    float* y1   = ws + 401408;     // [32][1024]
    float* x1   = ws + 434176;     // [32][1024]
    float* hbuf = ws + 466944;     // [32][4096]          = 131072
    float* part = ws + 598016;     // [4][32][1024]       = 131072

    // 1) fused QKV projection (writes q, ik, iv into qkv buffer)
    gemv_k1024<false, true, false><<<dim3(192, 1), 256, 0, stream>>>(
        x, HDIM, 0, qkvw, HDIM, 0, qkvb, nullptr, 0, qkv, 3 * HDIM, 0, 3 * HDIM);

    // 2) ik/iv outputs
    copy_ikiv<<<128, 256, 0, stream>>>(qkv, out);

    // 3) attention pass 1: streaming chunk partials (256 blocks = 1/CU)
    attn_part<<<BATCH * NCHUNK, 1024, 0, stream>>>(qkv, kc, vc, pacc, pmb, plb);

    // 3b) attention pass 2: merge chunks
    attn_finish<<<BATCH, 1024, 0, stream>>>(pacc, pmb, plb, attn);

    // 4) output projection + residual
    gemv_k1024<false, true, true><<<dim3(64, 1), 256, 0, stream>>>(
        attn, HDIM, 0, outw, HDIM, 0, outb, x, HDIM, y1, HDIM, 0, HDIM);

    // 5) LayerNorm 1
    ln_kernel<<<BATCH, 256, 0, stream>>>(y1, nw1, nb1, x1);

    // 6) MLP up + ReLU
    gemv_k1024<true, true, false><<<dim3(256, 1), 256, 0, stream>>>(
        x1, HDIM, 0, mw1, HDIM, 0, mb1, nullptr, 0, hbuf, FFDIM, 0, FFDIM);

    // 7) MLP down, split-K into 4 deterministic partials
    gemv_k1024<false, false, false><<<dim3(64, 4), 256, 0, stream>>>(
        hbuf, FFDIM, HDIM, mw2, FFDIM, HDIM, nullptr, nullptr, 0,
        part, HDIM, BATCH * HDIM, HDIM);

    // 8) reduce partials + bias + residual + LayerNorm 2 -> x output
    mlp2_finish<<<BATCH, 256, 0, stream>>>(part, x1, mb2, nw2, nb2, out);
}

// Round 3
// 227.309 us; speedup vs baseline: 1.1173x; 1.1173x over previous
//
#include <hip/hip_runtime.h>

#define BATCH 32
#define KVLEN 2048
#define HDIM 1024
#define NHEAD 16
#define DHEAD 64
#define FFDIM 4096
#define LN_EPS 1e-5f
#define NCHUNK 16
#define ROWS_PER_BLOCK 128   // 8 waves * 16 rows
#define ROWS_PER_WAVE 16

// ---------------------------------------------------------------------------
// GEMV over K=1024: out[b][j] = act(dot(in[b,:], W[j,:]) [+bias] [+res])
// One wave owns 4 consecutive j rows; weight fragments persist in registers
// across the 32-batch loop. Merged-tree reduction (7 shuffles / batch).
// DUP_IKIV: rows j>=1024 are also ik/iv -> duplicate into out_extra (d_out).
// ---------------------------------------------------------------------------
template<bool RELU, bool HAS_BIAS, bool HAS_RES, bool DUP_IKIV>
__global__ __launch_bounds__(256) void gemv_k1024(
    const float* __restrict__ in, int in_bstride, int in_coff,
    const float* __restrict__ W, int w_jstride, int w_coff,
    const float* __restrict__ bias,
    const float* __restrict__ res, int res_bstride,
    float* __restrict__ out, int out_bstride, int out_coff,
    float* __restrict__ out_extra,
    int nJ)
{
    const int wave = (int)((blockIdx.x * blockDim.x + threadIdx.x) >> 6);
    const int lane = (int)(threadIdx.x & 63);
    const int j0 = wave * 4;
    if (j0 >= nJ) return;
    const int c = (int)blockIdx.y;
    const float* inp = in + (size_t)c * in_coff;
    const float* Wp  = W  + (size_t)c * w_coff;
    float* outp      = out + (size_t)c * out_coff;

    float4 w[4][4];
#pragma unroll
    for (int jj = 0; jj < 4; ++jj) {
        const float4* wr = (const float4*)(Wp + (size_t)(j0 + jj) * w_jstride);
#pragma unroll
        for (int i = 0; i < 4; ++i) w[jj][i] = wr[lane + i * 64];
    }

    for (int b = 0; b < BATCH; ++b) {
        const float4* xr = (const float4*)(inp + (size_t)b * in_bstride);
        float4 xv[4];
#pragma unroll
        for (int i = 0; i < 4; ++i) xv[i] = xr[lane + i * 64];
        float s[4];
#pragma unroll
        for (int jj = 0; jj < 4; ++jj) {
            float a = 0.f;
#pragma unroll
            for (int i = 0; i < 4; ++i)
                a += w[jj][i].x * xv[i].x + w[jj][i].y * xv[i].y
                   + w[jj][i].z * xv[i].z + w[jj][i].w * xv[i].w;
            s[jj] = a;
        }
        // merged tree: fold 4 values into 1 reg (3 shfl), then 4 butterfly levels
        const bool b0 = (lane & 1), b1 = (lane & 2);
        float a0 = b0 ? s[0] : s[1];
        float t0 = (b0 ? s[1] : s[0]) + __shfl_xor(a0, 1, 64);
        float a1 = b0 ? s[2] : s[3];
        float t1 = (b0 ? s[3] : s[2]) + __shfl_xor(a1, 1, 64);
        float a2 = b1 ? t0 : t1;
        float v  = (b1 ? t1 : t0) + __shfl_xor(a2, 2, 64);
        v += __shfl_xor(v, 4, 64);
        v += __shfl_xor(v, 8, 64);
        v += __shfl_xor(v, 16, 64);
        v += __shfl_xor(v, 32, 64);
        if (lane < 4) {
            const int j = j0 + lane;
            float o = v;
            if (HAS_BIAS) o += bias[j];
            if (HAS_RES)  o += res[(size_t)b * res_bstride + j];
            if (RELU)     o = fmaxf(o, 0.f);
            outp[(size_t)b * out_bstride + j] = o;
            if (DUP_IKIV && j >= 1024) {
                const int base = (j >= 2048) ? 65536 : 32768;
                out_extra[base + b * 1024 + (j & 1023)] = o;
            }
        }
    }
}

// ---------------------------------------------------------------------------
// Attention pass 1: block = (b, chunk of 128 rows), 512 threads = 8 waves,
// 16 rows per wave in sub-batches of 4. Contiguous-pass layout: pass i,
// lane l covers dims i*256 + l*4 .. +3 (every load instr = contiguous 1KB).
// Head of (i,l) = 4i + (l>>4); 16-lane reduce (4 shfl) per (row, pass).
// Per-lane online softmax tracks 4 head-chains; sub-batched to amortize the
// dependency chain and keep ~16 loads in flight.
// ---------------------------------------------------------------------------
__global__ __launch_bounds__(512) void attn_part(
    const float* __restrict__ qkv,       // [32][3072]
    const float* __restrict__ k_cache,   // [32][2048][1024]
    const float* __restrict__ v_cache,
    float* __restrict__ pacc,            // [32][16][1024] (plain dim order)
    float* __restrict__ pm,              // [32][16][16]
    float* __restrict__ pl)              // [32][16][16]
{
    const int b = (int)(blockIdx.x >> 4);
    const int c = (int)(blockIdx.x & 15);
    const int tid = (int)threadIdx.x;
    const int w = tid >> 6;      // wave 0..7
    const int l = tid & 63;

    // q fragments: q[i] = q_vec[i*256 + l*4 .. +3]
    const float* qrow = qkv + (size_t)b * 3072 + l * 4;
    float4 q[4];
#pragma unroll
    for (int i = 0; i < 4; ++i) q[i] = *(const float4*)(qrow + i * 256);

    const size_t rowbase = ((size_t)b * KVLEN + c * ROWS_PER_BLOCK + w * ROWS_PER_WAVE) * HDIM + l * 4;
    const float* kb = k_cache + rowbase;
    const float* vb = v_cache + rowbase;

    float m[4], ls[4];
    float4 acc[4];
#pragma unroll
    for (int i = 0; i < 4; ++i) {
        m[i] = -1e30f; ls[i] = 0.f;
        acc[i] = make_float4(0.f, 0.f, 0.f, 0.f);
    }

    for (int sb = 0; sb < 4; ++sb) {
        // --- K loads: 16 independent contiguous-1KB instructions ---
        float4 kf[4][4];
#pragma unroll
        for (int r = 0; r < 4; ++r)
#pragma unroll
            for (int i = 0; i < 4; ++i)
                kf[r][i] = *(const float4*)(kb + (size_t)(sb * 4 + r) * HDIM + i * 256);
        // --- dots + 16-lane reduce ---
        float s[4][4];
#pragma unroll
        for (int r = 0; r < 4; ++r) {
#pragma unroll
            for (int i = 0; i < 4; ++i) {
                float d = kf[r][i].x * q[i].x + kf[r][i].y * q[i].y
                        + kf[r][i].z * q[i].z + kf[r][i].w * q[i].w;
                d += __shfl_xor(d, 1, 64);
                d += __shfl_xor(d, 2, 64);
                d += __shfl_xor(d, 4, 64);
                d += __shfl_xor(d, 8, 64);
                s[r][i] = d * 0.125f;
            }
        }
        // --- V loads issued before softmax VALU ---
        float4 vf[4][4];
#pragma unroll
        for (int r = 0; r < 4; ++r)
#pragma unroll
            for (int i = 0; i < 4; ++i)
                vf[r][i] = *(const float4*)(vb + (size_t)(sb * 4 + r) * HDIM + i * 256);
        // --- batched online softmax update (4 chains/lane) ---
#pragma unroll
        for (int i = 0; i < 4; ++i) {
            float mn = fmaxf(fmaxf(s[0][i], s[1][i]), fmaxf(s[2][i], s[3][i]));
            mn = fmaxf(mn, m[i]);
            const float corr = __expf(m[i] - mn);
            const float p0 = __expf(s[0][i] - mn);
            const float p1 = __expf(s[1][i] - mn);
            const float p2 = __expf(s[2][i] - mn);
            const float p3 = __expf(s[3][i] - mn);
            ls[i] = ls[i] * corr + (p0 + p1) + (p2 + p3);
            m[i] = mn;
            acc[i].x = acc[i].x * corr + p0 * vf[0][i].x + p1 * vf[1][i].x + p2 * vf[2][i].x + p3 * vf[3][i].x;
            acc[i].y = acc[i].y * corr + p0 * vf[0][i].y + p1 * vf[1][i].y + p2 * vf[2][i].y + p3 * vf[3][i].y;
            acc[i].z = acc[i].z * corr + p0 * vf[0][i].z + p1 * vf[1][i].z + p2 * vf[2][i].z + p3 * vf[3][i].z;
            acc[i].w = acc[i].w * corr + p0 * vf[0][i].w + p1 * vf[1][i].w + p2 * vf[2][i].w + p3 * vf[3][i].w;
        }
    }

    // --- cross-wave combine in LDS (once per block) ---
    __shared__ float sacc[8][1024];
    __shared__ float smm[8][16], sll[8][16];
#pragma unroll
    for (int i = 0; i < 4; ++i)
        *(float4*)&sacc[w][i * 256 + l * 4] = acc[i];
    if ((l & 15) == 0) {
        const int g = l >> 4;
#pragma unroll
        for (int i = 0; i < 4; ++i) { smm[w][i * 4 + g] = m[i]; sll[w][i * 4 + g] = ls[i]; }
    }
    __syncthreads();

#pragma unroll
    for (int half = 0; half < 2; ++half) {
        const int p = tid + half * 512;
        const int h = p >> 6;
        float M = -1e30f;
#pragma unroll
        for (int w2 = 0; w2 < 8; ++w2) M = fmaxf(M, smm[w2][h]);
        float L = 0.f, o = 0.f;
#pragma unroll
        for (int w2 = 0; w2 < 8; ++w2) {
            const float f = __expf(smm[w2][h] - M);
            L += sll[w2][h] * f;
            o += sacc[w2][p] * f;
        }
        pacc[((size_t)b * NCHUNK + c) * 1024 + p] = o;
        if ((p & 63) == 0) {
            pm[((size_t)b * NCHUNK + c) * 16 + h] = M;
            pl[((size_t)b * NCHUNK + c) * 16 + h] = L;
        }
    }
}

// ---------------------------------------------------------------------------
// Attention pass 2: merge 16 chunk partials + appended token (row 2048).
// 1 block per batch, 1024 threads; wave h owns head h (64 dims).
// ---------------------------------------------------------------------------
__global__ __launch_bounds__(1024) void attn_finish(
    const float* __restrict__ qkv,
    const float* __restrict__ pacc, const float* __restrict__ pm,
    const float* __restrict__ pl, float* __restrict__ attn_out)
{
    const int b = (int)blockIdx.x;
    const int p = (int)threadIdx.x;
    const int h = p >> 6;
    const float qa = qkv[(size_t)b * 3072 + p];
    const float ka = qkv[(size_t)b * 3072 + 1024 + p];
    const float va = qkv[(size_t)b * 3072 + 2048 + p];
    float d = qa * ka;
#pragma unroll
    for (int off = 1; off < 64; off <<= 1) d += __shfl_xor(d, off, 64);
    const float s = d * 0.125f;

    float M = s;
#pragma unroll
    for (int c = 0; c < NCHUNK; ++c)
        M = fmaxf(M, pm[((size_t)b * NCHUNK + c) * 16 + h]);
    const float pa = __expf(s - M);
    float L = pa, o = pa * va;
#pragma unroll
    for (int c = 0; c < NCHUNK; ++c) {
        const float f = __expf(pm[((size_t)b * NCHUNK + c) * 16 + h] - M);
        L += pl[((size_t)b * NCHUNK + c) * 16 + h] * f;
        o += pacc[((size_t)b * NCHUNK + c) * 1024 + p] * f;
    }
    attn_out[(size_t)b * HDIM + p] = o / L;
}

// ---------------------------------------------------------------------------
// Row LayerNorm: 1 block per batch row of 1024.
// ---------------------------------------------------------------------------
__global__ __launch_bounds__(256) void ln_kernel(const float* __restrict__ in,
    const float* __restrict__ w, const float* __restrict__ bv,
    float* __restrict__ out)
{
    const int b = (int)blockIdx.x, tid = (int)threadIdx.x;
    const float4 v = ((const float4*)(in + (size_t)b * HDIM))[tid];
    float sum = v.x + v.y + v.z + v.w;
    float sq  = v.x * v.x + v.y * v.y + v.z * v.z + v.w * v.w;
#pragma unroll
    for (int off = 1; off < 64; off <<= 1) {
        sum += __shfl_xor(sum, off, 64);
        sq  += __shfl_xor(sq,  off, 64);
    }
    __shared__ float s1[4], s2[4];
    const int wid = tid >> 6, lane = tid & 63;
    if (lane == 0) { s1[wid] = sum; s2[wid] = sq; }
    __syncthreads();
    sum = s1[0] + s1[1] + s1[2] + s1[3];
    sq  = s2[0] + s2[1] + s2[2] + s2[3];
    const float mu = sum * (1.f / HDIM);
    const float var = sq * (1.f / HDIM) - mu * mu;
    const float rstd = rsqrtf(var + LN_EPS);
    const float4 wv = ((const float4*)w)[tid];
    const float4 bb = ((const float4*)bv)[tid];
    float4 o;
    o.x = (v.x - mu) * rstd * wv.x + bb.x;
    o.y = (v.y - mu) * rstd * wv.y + bb.y;
    o.z = (v.z - mu) * rstd * wv.z + bb.z;
    o.w = (v.w - mu) * rstd * wv.w + bb.w;
    ((float4*)(out + (size_t)b * HDIM))[tid] = o;
}

// ---------------------------------------------------------------------------
// MLP2 finish: sum 4 split-K partials + bias + residual, then LayerNorm -> d_out
// ---------------------------------------------------------------------------
__global__ __launch_bounds__(256) void mlp2_finish(const float* __restrict__ part,
    const float* __restrict__ x1, const float* __restrict__ mbias,
    const float* __restrict__ w, const float* __restrict__ bv,
    float* __restrict__ out)
{
    const int b = (int)blockIdx.x, tid = (int)threadIdx.x;
    float4 v = make_float4(0.f, 0.f, 0.f, 0.f);
#pragma unroll
    for (int c = 0; c < 4; ++c) {
        const float4 p = ((const float4*)(part + (size_t)c * 32768 + (size_t)b * HDIM))[tid];
        v.x += p.x; v.y += p.y; v.z += p.z; v.w += p.w;
    }
    const float4 r  = ((const float4*)(x1 + (size_t)b * HDIM))[tid];
    const float4 mb = ((const float4*)mbias)[tid];
    v.x += r.x + mb.x; v.y += r.y + mb.y; v.z += r.z + mb.z; v.w += r.w + mb.w;

    float sum = v.x + v.y + v.z + v.w;
    float sq  = v.x * v.x + v.y * v.y + v.z * v.z + v.w * v.w;
#pragma unroll
    for (int off = 1; off < 64; off <<= 1) {
        sum += __shfl_xor(sum, off, 64);
        sq  += __shfl_xor(sq,  off, 64);
    }
    __shared__ float s1[4], s2[4];
    const int wid = tid >> 6, lane = tid & 63;
    if (lane == 0) { s1[wid] = sum; s2[wid] = sq; }
    __syncthreads();
    sum = s1[0] + s1[1] + s1[2] + s1[3];
    sq  = s2[0] + s2[1] + s2[2] + s2[3];
    const float mu = sum * (1.f / HDIM);
    const float var = sq * (1.f / HDIM) - mu * mu;
    const float rstd = rsqrtf(var + LN_EPS);
    const float4 wv = ((const float4*)w)[tid];
    const float4 bb = ((const float4*)bv)[tid];
    float4 o;
    o.x = (v.x - mu) * rstd * wv.x + bb.x;
    o.y = (v.y - mu) * rstd * wv.y + bb.y;
    o.z = (v.z - mu) * rstd * wv.z + bb.z;
    o.w = (v.w - mu) * rstd * wv.w + bb.w;
    ((float4*)(out + (size_t)b * HDIM))[tid] = o;
}

extern "C" void kernel_launch(void* const* d_in, const int* in_sizes, int n_in,
                              void* d_out, int out_size, void* d_ws, size_t ws_size,
                              hipStream_t stream) {
    const float* x     = (const float*)d_in[0];
    const float* kc    = (const float*)d_in[1];
    const float* vc    = (const float*)d_in[2];
    const float* qkvw  = (const float*)d_in[3];
    const float* qkvb  = (const float*)d_in[4];
    const float* outw  = (const float*)d_in[5];
    const float* outb  = (const float*)d_in[6];
    const float* nw1   = (const float*)d_in[7];
    const float* nb1   = (const float*)d_in[8];
    const float* nw2   = (const float*)d_in[9];
    const float* nb2   = (const float*)d_in[10];
    const float* mw1   = (const float*)d_in[11];
    const float* mb1   = (const float*)d_in[12];
    const float* mw2   = (const float*)d_in[13];
    const float* mb2   = (const float*)d_in[14];
    float* out = (float*)d_out;

    float* ws   = (float*)d_ws;
    float* qkv  = ws;              // [32][3072]           = 98304
    float* pacc = ws + 98304;      // [32][16][1024]       = 524288
    float* pmb  = ws + 622592;     // [32][16][16]         = 8192
    float* plb  = ws + 630784;     // [32][16][16]         = 8192
    float* attn = ws + 638976;     // [32][1024]
    float* y1   = ws + 671744;     // [32][1024]
    float* x1   = ws + 704512;     // [32][1024]
    // pacc region is dead after attn_finish -> reuse for MLP buffers
    float* hbuf = pacc;            // [32][4096]           = 131072
    float* part = pacc + 131072;   // [4][32][1024]        = 131072

    // 1) fused QKV projection (q|ik|iv into qkv buffer; ik/iv also -> d_out)
    gemv_k1024<false, true, false, true><<<dim3(192, 1), 256, 0, stream>>>(
        x, HDIM, 0, qkvw, HDIM, 0, qkvb, nullptr, 0, qkv, 3 * HDIM, 0, out, 3 * HDIM);

    // 2) attention pass 1: chunk partials (512 blocks, contiguous streaming)
    attn_part<<<BATCH * NCHUNK, 512, 0, stream>>>(qkv, kc, vc, pacc, pmb, plb);

    // 3) attention pass 2: merge chunks + appended token
    attn_finish<<<BATCH, 1024, 0, stream>>>(qkv, pacc, pmb, plb, attn);

    // 4) output projection + residual
    gemv_k1024<false, true, true, false><<<dim3(64, 1), 256, 0, stream>>>(
        attn, HDIM, 0, outw, HDIM, 0, outb, x, HDIM, y1, HDIM, 0, nullptr, HDIM);

    // 5) LayerNorm 1
    ln_kernel<<<BATCH, 256, 0, stream>>>(y1, nw1, nb1, x1);

    // 6) MLP up + ReLU
    gemv_k1024<true, true, false, false><<<dim3(256, 1), 256, 0, stream>>>(
        x1, HDIM, 0, mw1, HDIM, 0, mb1, nullptr, 0, hbuf, FFDIM, 0, nullptr, FFDIM);

    // 7) MLP down, split-K into 4 deterministic partials
    gemv_k1024<false, false, false, false><<<dim3(64, 4), 256, 0, stream>>>(
        hbuf, FFDIM, HDIM, mw2, FFDIM, HDIM, nullptr, nullptr, 0,
        part, HDIM, BATCH * HDIM, nullptr, HDIM);

    // 8) reduce partials + bias + residual + LayerNorm 2 -> x output
    mlp2_finish<<<BATCH, 256, 0, stream>>>(part, x1, mb2, nw2, nb2, out);
}